// Round 4
// baseline (178.406 us; speedup 1.0000x reference)
//
#include <hip/hip_runtime.h>

typedef unsigned short u16;
typedef unsigned int u32;
typedef __attribute__((ext_vector_type(8))) short bf16x8;
typedef __attribute__((ext_vector_type(4))) float f32x4;

#define MFMA(a, b, c) __builtin_amdgcn_mfma_f32_16x16x32_bf16((a), (b), (c), 0, 0, 0)

// round-to-nearest-even f32 -> bf16
static __device__ __forceinline__ u16 f2bf(float x) {
  u32 u = __float_as_uint(x);
  u += 0x7FFFu + ((u >> 16) & 1u);
  return (u16)(u >> 16);
}
// pack two f32 -> (bf16(hi)<<16)|bf16(lo), truncating (hot paths)
static __device__ __forceinline__ u32 packbf_t(float hi, float lo) {
  return __builtin_amdgcn_perm(__float_as_uint(hi), __float_as_uint(lo), 0x07060302u);
}
// rounded pack: lo | hi<<16
static __device__ __forceinline__ u32 packbf(float lo, float hi) {
  return (u32)f2bf(lo) | ((u32)f2bf(hi) << 16);
}

// ---------------------------------------------------------------------------
// Kernel 0: weight prep (bf16 conversion + gate-major permute of Wm).
// ---------------------------------------------------------------------------
__global__ void prep_kernel(const float* __restrict__ Wq, const float* __restrict__ Wk,
                            const float* __restrict__ Wk2, const float* __restrict__ Wv,
                            const float* __restrict__ Wv2, const float* __restrict__ Wz,
                            const float* __restrict__ Wm, const float* __restrict__ bm,
                            u16* __restrict__ W5, u16* __restrict__ Wzb,
                            u16* __restrict__ Wmb, float* __restrict__ bmp) {
  const int id = blockIdx.x * 256 + threadIdx.x;
  if (id < 20480) {
    const int wi = id >> 12, e = id & 4095;
    const float* src = wi == 0 ? Wq : wi == 1 ? Wk : wi == 2 ? Wk2 : wi == 3 ? Wv : Wv2;
    W5[id] = f2bf(src[e]);
  } else if (id < 36864) {
    const int e = id - 20480;
    Wzb[e] = f2bf(Wz[e]);
  } else if (id < 73728) {
    const int e = id - 36864;
    const int p = e / 192, k = e % 192;
    const int hb2 = p / 96, r1 = p % 96, ctl = r1 / 48, r2 = r1 % 48;
    const int g = r2 >> 4, mm = r2 & 15;
    const int o = g * 64 + (hb2 * 2 + ctl) * 16 + mm;
    Wmb[p * 192 + k] = f2bf(Wm[o * 192 + k]);
  } else if (id < 73920) {
    const int p = id - 73728;
    const int hb2 = p / 96, r1 = p % 96, ctl = r1 / 48, r2 = r1 % 48;
    const int g = r2 >> 4, mm = r2 & 15;
    const int o = g * 64 + (hb2 * 2 + ctl) * 16 + mm;
    bmp[p] = bm[o];
  }
}

// ---------------------------------------------------------------------------
// Kernel 1: 1x1-conv projections via bf16 MFMA, packed uint2 stores.
// grid (16 ntiles, 16 batches, 2).
// ---------------------------------------------------------------------------
__global__ __launch_bounds__(256) void proj_kernel(
    const float* __restrict__ h, const float* __restrict__ m_,
    const float* __restrict__ bq, const float* __restrict__ bk,
    const float* __restrict__ bk2, const float* __restrict__ bv,
    const float* __restrict__ bv2, const u16* __restrict__ W5,
    u16* __restrict__ Qb, u16* __restrict__ Khb, u16* __restrict__ Kmb,
    u16* __restrict__ Vhb, u16* __restrict__ Vmb, u16* __restrict__ hbuf)
{
  const int b = blockIdx.y, n0 = blockIdx.x * 64, z = blockIdx.z;
  __shared__ __align__(16) u16 xt[64][72];  // [px][c] bf16
  const int tid = threadIdx.x;
  const float* __restrict__ X = z ? m_ : h;

  {
    const int px = tid & 63, c0 = (tid >> 6) * 16;
#pragma unroll
    for (int i = 0; i < 8; ++i) {
      const int c = c0 + 2 * i;
      const float f0 = X[(b * 64 + c) * 1024 + n0 + px];
      const float f1 = X[(b * 64 + c + 1) * 1024 + n0 + px];
      *(u32*)&xt[px][c] = packbf(f0, f1);
    }
  }
  __syncthreads();

  const int lane = tid & 63, w = tid >> 6;  // w = 16-px tile
  const int mm = lane & 15, q = lane >> 4;

  const bf16x8 xa0 = *(const bf16x8*)&xt[w * 16 + mm][q * 8];
  const bf16x8 xa1 = *(const bf16x8*)&xt[w * 16 + mm][32 + q * 8];

  // (B,N,64): rows=channel (A=W). Lane -> 4 contiguous channels at px=w*16+mm.
  auto qk_store = [&](u16* dst, const u16* Wb, const float* bias) {
#pragma unroll
    for (int ot = 0; ot < 4; ++ot) {
      const bf16x8 wb0 = *(const bf16x8*)(Wb + (ot * 16 + mm) * 64 + q * 8);
      const bf16x8 wb1 = *(const bf16x8*)(Wb + (ot * 16 + mm) * 64 + 32 + q * 8);
      const float4 b4 = *(const float4*)(bias + ot * 16 + q * 4);
      f32x4 d = {b4.x, b4.y, b4.z, b4.w};
      d = MFMA(wb0, xa0, d);
      d = MFMA(wb1, xa1, d);
      uint2 val;
      val.x = packbf(d[0], d[1]);
      val.y = packbf(d[2], d[3]);
      *(uint2*)(dst + (b * 1024 + n0 + w * 16 + mm) * 64 + ot * 16 + q * 4) = val;
    }
  };
  // (B,C,N): rows=pixel (A=x). Lane -> 4 contiguous px at channel ot*16+mm.
  auto v_store = [&](u16* dst, const u16* Wb, const float* bias) {
#pragma unroll
    for (int ot = 0; ot < 4; ++ot) {
      const bf16x8 wb0 = *(const bf16x8*)(Wb + (ot * 16 + mm) * 64 + q * 8);
      const bf16x8 wb1 = *(const bf16x8*)(Wb + (ot * 16 + mm) * 64 + 32 + q * 8);
      const float bb = bias[ot * 16 + mm];
      f32x4 d = {bb, bb, bb, bb};
      d = MFMA(xa0, wb0, d);
      d = MFMA(xa1, wb1, d);
      uint2 val;
      val.x = packbf(d[0], d[1]);
      val.y = packbf(d[2], d[3]);
      *(uint2*)(dst + (b * 64 + ot * 16 + mm) * 1024 + n0 + w * 16 + q * 4) = val;
    }
  };

  if (z == 0) {
    qk_store(Qb, W5, bq);
    qk_store(Khb, W5 + 4096, bk);
    v_store(Vhb, W5 + 3 * 4096, bv);
    const int px = tid >> 2, sg = tid & 3;
    u32* dst = (u32*)(hbuf + (b * 1024 + n0 + px) * 64 + sg * 16);
    const u16* srcr = &xt[px][sg * 16];
#pragma unroll
    for (int j = 0; j < 8; ++j) dst[j] = *(const u32*)(srcr + 2 * j);
  } else {
    qk_store(Kmb, W5 + 2 * 4096, bk2);
    v_store(Vmb, W5 + 4 * 4096, bv2);
  }
}

// ---------------------------------------------------------------------------
// Kernel 2: fused attention. One 16-query tile per wave over ALL 1024 keys:
// no LDS, no barriers, waves independent. S^T = K·Q^T (A=K) keeps exp in
// register; C/D->B-operand fix = 8 bpermutes + 4 selects (verified mapping).
// Explicit 2-deep register double-buffer + #pragma unroll 1 caps VGPR
// pressure (~100) -- round-3's full-unroll spilled to scratch (38 MB writes).
// grid 512 = 16 b (XCD-affine) x 2 br x 16 qtiles; block 256 = 4 waves.
// ---------------------------------------------------------------------------
struct Chunk { bf16x8 f[8]; };  // [0..3]=K t0lo,t0hi,t1lo,t1hi; [4..7]=V ct0..3

__global__ __launch_bounds__(256) void attn_kernel(
    const u16* __restrict__ Qb, const u16* __restrict__ Khb,
    const u16* __restrict__ Kmb, const u16* __restrict__ Vhb,
    const u16* __restrict__ Vmb, u16* __restrict__ Ztb)
{
  const int id = blockIdx.x;
  const int b = id & 15;            // batch -> fixed XCD
  const int br = (id >> 4) & 1;
  const int qt = id >> 5;           // 0..15
  const u16* __restrict__ K = br ? Kmb : Khb;
  const u16* __restrict__ V = br ? Vmb : Vhb;

  const int tid = threadIdx.x, w = tid >> 6, lane = tid & 63;
  const int mm = lane & 15, q = lane >> 4;
  const int q0 = qt * 64 + w * 16;  // this wave's 16 queries

  const u16* Qp = Qb + (b * 1024 + q0 + mm) * 64;
  const bf16x8 qa0 = *(const bf16x8*)(Qp + q * 8);
  const bf16x8 qa1 = *(const bf16x8*)(Qp + 32 + q * 8);

  f32x4 z[4];
#pragma unroll
  for (int ct = 0; ct < 4; ++ct) z[ct] = (f32x4){0.f, 0.f, 0.f, 0.f};
  float rp = 0.f;

  const int base = (2 * (q & 1)) * 16 + mm;  // src lane for exchange
  const bool hiq = q >= 2;

  auto loadch = [&](int kb, Chunk& c) {
    const u16* Kp0 = K + (b * 1024 + kb + mm) * 64;
    c.f[0] = *(const bf16x8*)(Kp0 + q * 8);
    c.f[1] = *(const bf16x8*)(Kp0 + 32 + q * 8);
    c.f[2] = *(const bf16x8*)(Kp0 + 1024 + q * 8);        // +16 keys
    c.f[3] = *(const bf16x8*)(Kp0 + 1024 + 32 + q * 8);
#pragma unroll
    for (int ct = 0; ct < 4; ++ct)
      c.f[4 + ct] = *(const bf16x8*)(V + (b * 64 + ct * 16 + mm) * 1024 + kb + q * 8);
  };

  auto compute = [&](const Chunk& c) {
    u32 P0, P1, P2, P3;
    {
      f32x4 s = {0.f, 0.f, 0.f, 0.f};
      s = MFMA(c.f[0], qa0, s);
      s = MFMA(c.f[1], qa1, s);
      const float e0 = __expf(s[0]), e1 = __expf(s[1]);
      const float e2 = __expf(s[2]), e3 = __expf(s[3]);
      rp += (e0 + e1) + (e2 + e3);
      P0 = packbf_t(e1, e0);
      P1 = packbf_t(e3, e2);
    }
    {
      f32x4 s = {0.f, 0.f, 0.f, 0.f};
      s = MFMA(c.f[2], qa0, s);
      s = MFMA(c.f[3], qa1, s);
      const float e0 = __expf(s[0]), e1 = __expf(s[1]);
      const float e2 = __expf(s[2]), e3 = __expf(s[3]);
      rp += (e0 + e1) + (e2 + e3);
      P2 = packbf_t(e1, e0);
      P3 = packbf_t(e3, e2);
    }
    // exchange: lane(q,mm) gathers keys q*8..q*8+7 (B-operand layout)
    const u32 l0 = (u32)__shfl((int)P0, base),      h0 = (u32)__shfl((int)P2, base);
    const u32 l1 = (u32)__shfl((int)P1, base),      h1 = (u32)__shfl((int)P3, base);
    const u32 l2 = (u32)__shfl((int)P0, base + 16), h2 = (u32)__shfl((int)P2, base + 16);
    const u32 l3 = (u32)__shfl((int)P1, base + 16), h3 = (u32)__shfl((int)P3, base + 16);
    union { u32 u[4]; bf16x8 v; } bu;
    bu.u[0] = hiq ? h0 : l0;
    bu.u[1] = hiq ? h1 : l1;
    bu.u[2] = hiq ? h2 : l2;
    bu.u[3] = hiq ? h3 : l3;
#pragma unroll
    for (int ct = 0; ct < 4; ++ct) z[ct] = MFMA(c.f[4 + ct], bu.v, z[ct]);
  };

  Chunk fA, fB;
  loadch(0, fA);
#pragma unroll 1
  for (int cc = 0; cc < 16; ++cc) {   // 16 x 64 keys; 2 chunks of 32 per iter
    loadch(cc * 64 + 32, fB);
    compute(fA);
    if (cc < 15) loadch(cc * 64 + 64, fA);
    compute(fB);
  }

  // rowsum for query mm: reduce over the 4 quads, then normalize + store.
  rp += __shfl_xor(rp, 16);
  rp += __shfl_xor(rp, 32);
  const float rinv = __builtin_amdgcn_rcpf(rp);
  u16* Zr = Ztb + (b * 1024 + q0 + mm) * 128 + br * 64 + q * 4;
#pragma unroll
  for (int ct = 0; ct < 4; ++ct) {
    uint2 val;
    val.x = packbf(z[ct][0] * rinv, z[ct][1] * rinv);
    val.y = packbf(z[ct][2] * rinv, z[ct][3] * rinv);
    *(uint2*)(Zr + ct * 16) = val;
  }
}

// ---------------------------------------------------------------------------
// Kernel 3: fused zproj (128->128) + final (192->192) + gates, all MFMA.
// grid (32,16).
// ---------------------------------------------------------------------------
__global__ __launch_bounds__(256) void tail_kernel(
    const u16* __restrict__ Ztb, const u16* __restrict__ hbuf,
    const float* __restrict__ m_, const u16* __restrict__ Wzb,
    const float* __restrict__ bz, const u16* __restrict__ Wmb,
    const float* __restrict__ bmp, float* __restrict__ out)
{
  const int b = blockIdx.y, n0 = blockIdx.x * 32;
  __shared__ __align__(16) u16 zp[32][136];  // bf16 Zp tile [px][c]
  const int tid = threadIdx.x, lane = tid & 63, wv = tid >> 6;
  const int mm = lane & 15, q = lane >> 4;
  const int pxt = wv & 1, oh = wv >> 1;

  // ---- Phase A: Zp = Wz @ [Zh;Zm] + bz  (A=W: lane rows = contiguous o-ch)
  {
    bf16x8 za[4];
#pragma unroll
    for (int ks = 0; ks < 4; ++ks)
      za[ks] = *(const bf16x8*)(Ztb + (b * 1024 + n0 + pxt * 16 + mm) * 128 +
                                ks * 32 + q * 8);
#pragma unroll
    for (int ot = 0; ot < 4; ++ot) {
      const int o0 = oh * 64 + ot * 16;
      const float4 b4 = *(const float4*)(bz + o0 + q * 4);
      f32x4 d = {b4.x, b4.y, b4.z, b4.w};
#pragma unroll
      for (int ks = 0; ks < 4; ++ks) {
        const bf16x8 wb = *(const bf16x8*)(Wzb + (o0 + mm) * 128 + ks * 32 + q * 8);
        d = MFMA(wb, za[ks], d);
      }
      uint2 val;
      val.x = packbf(d[0], d[1]);
      val.y = packbf(d[2], d[3]);
      *(uint2*)&zp[pxt * 16 + mm][o0 + q * 4] = val;
    }
  }
  __syncthreads();

  // ---- Phase B: combined = Wm @ [Zp; h] + bm (rows gate-major-permuted)
  {
    const int hb2 = oh;
    bf16x8 fa[6];
#pragma unroll
    for (int ks = 0; ks < 4; ++ks)
      fa[ks] = *(const bf16x8*)&zp[pxt * 16 + mm][ks * 32 + q * 8];
    {
      const u16* hp = hbuf + (b * 1024 + n0 + pxt * 16 + mm) * 64;
      fa[4] = *(const bf16x8*)(hp + q * 8);
      fa[5] = *(const bf16x8*)(hp + 32 + q * 8);
    }
    f32x4 dd[6];
#pragma unroll
    for (int j = 0; j < 6; ++j) {
      const int p = hb2 * 96 + j * 16 + mm;
      const float bb = bmp[p];
      f32x4 d = {bb, bb, bb, bb};
#pragma unroll
      for (int ks = 0; ks < 6; ++ks) {
        const bf16x8 wb = *(const bf16x8*)(Wmb + p * 192 + ks * 32 + q * 8);
        d = MFMA(fa[ks], wb, d);
      }
      dd[j] = d;
    }
#pragma unroll
    for (int ctl = 0; ctl < 2; ++ctl) {
      const int c = (hb2 * 2 + ctl) * 16 + mm;
      const int px = n0 + pxt * 16 + q * 4;
      const float4 mold = *(const float4*)(m_ + (b * 64 + c) * 1024 + px);
      float4 nh, nm;
#pragma unroll
      for (int r = 0; r < 4; ++r) {
        const float xo = dd[ctl * 3 + 0][r];
        const float xg = dd[ctl * 3 + 1][r];
        const float xi = dd[ctl * 3 + 2][r];
        const float si = __builtin_amdgcn_rcpf(1.f + __expf(-xi));
        const float th = 1.f - 2.f * __builtin_amdgcn_rcpf(__expf(2.f * xg) + 1.f);
        const float so = __builtin_amdgcn_rcpf(1.f + __expf(-xo));
        const float mo = ((const float*)&mold)[r];
        const float nmv = (1.f - si) * mo + si * th;
        ((float*)&nm)[r] = nmv;
        ((float*)&nh)[r] = so * nmv;
      }
      *(float4*)(out + (b * 64 + c) * 1024 + px) = nh;
      *(float4*)(out + 1048576 + (b * 64 + c) * 1024 + px) = nm;
    }
  }
}

// ---------------------------------------------------------------------------
extern "C" void kernel_launch(void* const* d_in, const int* in_sizes, int n_in,
                              void* d_out, int out_size, void* d_ws, size_t ws_size,
                              hipStream_t stream) {
  const float* h   = (const float*)d_in[0];
  const float* m   = (const float*)d_in[1];
  const float* Wq  = (const float*)d_in[2];
  const float* bq  = (const float*)d_in[3];
  const float* Wk  = (const float*)d_in[4];
  const float* bk  = (const float*)d_in[5];
  const float* Wk2 = (const float*)d_in[6];
  const float* bk2 = (const float*)d_in[7];
  const float* Wv  = (const float*)d_in[8];
  const float* bv  = (const float*)d_in[9];
  const float* Wv2 = (const float*)d_in[10];
  const float* bv2 = (const float*)d_in[11];
  const float* Wz  = (const float*)d_in[12];
  const float* bz  = (const float*)d_in[13];
  const float* Wm  = (const float*)d_in[14];
  const float* bm  = (const float*)d_in[15];
  float* out = (float*)d_out;

  char* ws = (char*)d_ws;
  const size_t MB = 1024 * 1024;
  u16* Qb   = (u16*)(ws + 0 * MB);       // (B,N,64)
  u16* Khb  = (u16*)(ws + 2 * MB);
  u16* Kmb  = (u16*)(ws + 4 * MB);
  u16* Vhb  = (u16*)(ws + 6 * MB);       // (B,C,N)
  u16* Vmb  = (u16*)(ws + 8 * MB);
  u16* hbuf = (u16*)(ws + 10 * MB);      // (B,N,64)
  u16* Ztb  = (u16*)(ws + 12 * MB);      // (B,N,128)
  u16* W5   = (u16*)(ws + 16 * MB);               // 5x 64x64 bf16
  u16* Wzb  = (u16*)(ws + 16 * MB + 40960);       // 128x128
  u16* Wmb  = (u16*)(ws + 16 * MB + 73728);       // 192x192 permuted
  float* bmp = (float*)(ws + 16 * MB + 147456);   // 192 permuted

  prep_kernel<<<289, 256, 0, stream>>>(Wq, Wk, Wk2, Wv, Wv2, Wz, Wm, bm,
                                       W5, Wzb, Wmb, bmp);
  proj_kernel<<<dim3(16, 16, 2), 256, 0, stream>>>(h, m, bq, bk, bk2, bv, bv2, W5,
                                                   Qb, Khb, Kmb, Vhb, Vmb, hbuf);
  attn_kernel<<<512, 256, 0, stream>>>(Qb, Khb, Kmb, Vhb, Vmb, Ztb);
  tail_kernel<<<dim3(32, 16), 256, 0, stream>>>(Ztb, hbuf, m, Wzb, bz, Wmb, bmp, out);
}

// Round 5
// 141.651 us; speedup vs baseline: 1.2595x; 1.2595x over previous
//
#include <hip/hip_runtime.h>

typedef unsigned short u16;
typedef unsigned int u32;
typedef __attribute__((ext_vector_type(8))) short bf16x8;
typedef __attribute__((ext_vector_type(4))) float f32x4;

#define MFMA(a, b, c) __builtin_amdgcn_mfma_f32_16x16x32_bf16((a), (b), (c), 0, 0, 0)

// round-to-nearest-even f32 -> bf16
static __device__ __forceinline__ u16 f2bf(float x) {
  u32 u = __float_as_uint(x);
  u += 0x7FFFu + ((u >> 16) & 1u);
  return (u16)(u >> 16);
}
// pack two f32 -> (bf16(hi)<<16)|bf16(lo), truncating (hot paths)
static __device__ __forceinline__ u32 packbf_t(float hi, float lo) {
  return __builtin_amdgcn_perm(__float_as_uint(hi), __float_as_uint(lo), 0x07060302u);
}
// rounded pack: lo | hi<<16
static __device__ __forceinline__ u32 packbf(float lo, float hi) {
  return (u32)f2bf(lo) | ((u32)f2bf(hi) << 16);
}

// ---------------------------------------------------------------------------
// Kernel 0: weight prep (bf16 conversion + gate-major permute of Wm).
// ---------------------------------------------------------------------------
__global__ void prep_kernel(const float* __restrict__ Wq, const float* __restrict__ Wk,
                            const float* __restrict__ Wk2, const float* __restrict__ Wv,
                            const float* __restrict__ Wv2, const float* __restrict__ Wz,
                            const float* __restrict__ Wm, const float* __restrict__ bm,
                            u16* __restrict__ W5, u16* __restrict__ Wzb,
                            u16* __restrict__ Wmb, float* __restrict__ bmp) {
  const int id = blockIdx.x * 256 + threadIdx.x;
  if (id < 20480) {
    const int wi = id >> 12, e = id & 4095;
    const float* src = wi == 0 ? Wq : wi == 1 ? Wk : wi == 2 ? Wk2 : wi == 3 ? Wv : Wv2;
    W5[id] = f2bf(src[e]);
  } else if (id < 36864) {
    const int e = id - 20480;
    Wzb[e] = f2bf(Wz[e]);
  } else if (id < 73728) {
    const int e = id - 36864;
    const int p = e / 192, k = e % 192;
    const int hb2 = p / 96, r1 = p % 96, ctl = r1 / 48, r2 = r1 % 48;
    const int g = r2 >> 4, mm = r2 & 15;
    const int o = g * 64 + (hb2 * 2 + ctl) * 16 + mm;
    Wmb[p * 192 + k] = f2bf(Wm[o * 192 + k]);
  } else if (id < 73920) {
    const int p = id - 73728;
    const int hb2 = p / 96, r1 = p % 96, ctl = r1 / 48, r2 = r1 % 48;
    const int g = r2 >> 4, mm = r2 & 15;
    const int o = g * 64 + (hb2 * 2 + ctl) * 16 + mm;
    bmp[p] = bm[o];
  }
}

// ---------------------------------------------------------------------------
// Kernel 1: 1x1-conv projections via bf16 MFMA, packed uint2 stores.
// Q/K: (B,N,64). V: BLOCKED (b, kc=n/64, c, 64keys) so attn can stage 64-key
// V chunks as contiguous 8KB. grid (16 ntiles, 16 batches, 2).
// ---------------------------------------------------------------------------
__global__ __launch_bounds__(256) void proj_kernel(
    const float* __restrict__ h, const float* __restrict__ m_,
    const float* __restrict__ bq, const float* __restrict__ bk,
    const float* __restrict__ bk2, const float* __restrict__ bv,
    const float* __restrict__ bv2, const u16* __restrict__ W5,
    u16* __restrict__ Qb, u16* __restrict__ Khb, u16* __restrict__ Kmb,
    u16* __restrict__ Vhb, u16* __restrict__ Vmb, u16* __restrict__ hbuf)
{
  const int b = blockIdx.y, n0 = blockIdx.x * 64, z = blockIdx.z;
  __shared__ __align__(16) u16 xt[64][72];  // [px][c] bf16
  const int tid = threadIdx.x;
  const float* __restrict__ X = z ? m_ : h;

  {
    const int px = tid & 63, c0 = (tid >> 6) * 16;
#pragma unroll
    for (int i = 0; i < 8; ++i) {
      const int c = c0 + 2 * i;
      const float f0 = X[(b * 64 + c) * 1024 + n0 + px];
      const float f1 = X[(b * 64 + c + 1) * 1024 + n0 + px];
      *(u32*)&xt[px][c] = packbf(f0, f1);
    }
  }
  __syncthreads();

  const int lane = tid & 63, w = tid >> 6;  // w = 16-px tile
  const int mm = lane & 15, q = lane >> 4;

  const bf16x8 xa0 = *(const bf16x8*)&xt[w * 16 + mm][q * 8];
  const bf16x8 xa1 = *(const bf16x8*)&xt[w * 16 + mm][32 + q * 8];

  // (B,N,64): rows=channel (A=W). Lane -> 4 contiguous channels at px=w*16+mm.
  auto qk_store = [&](u16* dst, const u16* Wb, const float* bias) {
#pragma unroll
    for (int ot = 0; ot < 4; ++ot) {
      const bf16x8 wb0 = *(const bf16x8*)(Wb + (ot * 16 + mm) * 64 + q * 8);
      const bf16x8 wb1 = *(const bf16x8*)(Wb + (ot * 16 + mm) * 64 + 32 + q * 8);
      const float4 b4 = *(const float4*)(bias + ot * 16 + q * 4);
      f32x4 d = {b4.x, b4.y, b4.z, b4.w};
      d = MFMA(wb0, xa0, d);
      d = MFMA(wb1, xa1, d);
      uint2 val;
      val.x = packbf(d[0], d[1]);
      val.y = packbf(d[2], d[3]);
      *(uint2*)(dst + (b * 1024 + n0 + w * 16 + mm) * 64 + ot * 16 + q * 4) = val;
    }
  };
  // blocked V: rows=pixel (A=x). offset = b*65536 + kc*4096 + c*64 + key.
  auto v_store = [&](u16* dst, const u16* Wb, const float* bias) {
#pragma unroll
    for (int ot = 0; ot < 4; ++ot) {
      const bf16x8 wb0 = *(const bf16x8*)(Wb + (ot * 16 + mm) * 64 + q * 8);
      const bf16x8 wb1 = *(const bf16x8*)(Wb + (ot * 16 + mm) * 64 + 32 + q * 8);
      const float bb = bias[ot * 16 + mm];
      f32x4 d = {bb, bb, bb, bb};
      d = MFMA(xa0, wb0, d);
      d = MFMA(xa1, wb1, d);
      uint2 val;
      val.x = packbf(d[0], d[1]);
      val.y = packbf(d[2], d[3]);
      *(uint2*)(dst + b * 65536 + blockIdx.x * 4096 + (ot * 16 + mm) * 64 +
                w * 16 + q * 4) = val;
    }
  };

  if (z == 0) {
    qk_store(Qb, W5, bq);
    qk_store(Khb, W5 + 4096, bk);
    v_store(Vhb, W5 + 3 * 4096, bv);
    const int px = tid >> 2, sg = tid & 3;
    u32* dst = (u32*)(hbuf + (b * 1024 + n0 + px) * 64 + sg * 16);
    const u16* srcr = &xt[px][sg * 16];
#pragma unroll
    for (int j = 0; j < 8; ++j) dst[j] = *(const u32*)(srcr + 2 * j);
  } else {
    qk_store(Kmb, W5 + 2 * 4096, bk2);
    v_store(Vmb, W5 + 4 * 4096, bv2);
  }
}

// ---------------------------------------------------------------------------
// Kernel 2: fused attention, flash-style with LDS-staged K/V double buffer.
// Block = 128 queries (4 waves x 2 qt), grid 256 = 8 qh x 2 br x 16 b
// (XCD-affine). Per 64-key chunk: 16KB K+V staged once by all threads
// (coalesced uint4, XOR-swizzled for conflict-free ds_read_b128), consumed
// by all 4 waves. S^T = K·Q^T; P layout fix via per-wave ps LDS round-trip
// (4 packed u32 writes + 1 b128 read per 32 keys; same-wave DS order, no
// barrier). Single-pass unnormalized softmax (|s| <~ 10).
// ---------------------------------------------------------------------------
__global__ __launch_bounds__(256) void attn_kernel(
    const u16* __restrict__ Qb, const u16* __restrict__ Khb,
    const u16* __restrict__ Kmb, const u16* __restrict__ Vhb,
    const u16* __restrict__ Vmb, u16* __restrict__ Ztb)
{
  const int id = blockIdx.x;
  const int b = id & 15;            // batch -> fixed XCD (b&7)
  const int br = (id >> 4) & 1;
  const int qh = id >> 5;           // 0..7
  const u16* __restrict__ K = (br ? Kmb : Khb) + b * 65536;
  const u16* __restrict__ V = (br ? Vmb : Vhb) + b * 65536;

  __shared__ __align__(16) u16 Kl[2][4096];   // [buf][key*64 + swz(pos)*8]
  __shared__ __align__(16) u16 Vl[2][4096];   // [buf][c*64  + swz(pos)*8]
  __shared__ __align__(16) u16 ps[4][16][40]; // per-wave P [query][key(32)+pad]

  const int tid = threadIdx.x, w = tid >> 6, lane = tid & 63;
  const int mm = lane & 15, q = lane >> 4, m7 = mm & 7;
  const int q0 = qh * 128 + w * 32;  // this wave's 32 queries

  // Q A-frags for 2 query tiles
  bf16x8 qa0[2], qa1[2];
#pragma unroll
  for (int qt = 0; qt < 2; ++qt) {
    const u16* Qp = Qb + (b * 1024 + q0 + qt * 16 + mm) * 64;
    qa0[qt] = *(const bf16x8*)(Qp + q * 8);
    qa1[qt] = *(const bf16x8*)(Qp + 32 + q * 8);
  }

  f32x4 z[2][4];
#pragma unroll
  for (int qt = 0; qt < 2; ++qt)
#pragma unroll
    for (int ct = 0; ct < 4; ++ct) z[qt][ct] = (f32x4){0.f, 0.f, 0.f, 0.f};
  float rp[2] = {0.f, 0.f};

  // staging: 512 K-units + 512 V-units of 16B; thread t handles u={t,256+t}.
  const int u0 = tid, u1 = 256 + tid;
  const int l0 = (((u0 & ~7) | ((u0 ^ (u0 >> 3)) & 7))) * 8;
  const int l1 = (((u1 & ~7) | ((u1 ^ (u1 >> 3)) & 7))) * 8;
  uint4 sk0, sk1, sv0, sv1;

  auto stage_load = [&](int kc) {
    const u16* Ks = K + kc * 4096;
    const u16* Vs = V + kc * 4096;
    sk0 = *(const uint4*)(Ks + u0 * 8);
    sk1 = *(const uint4*)(Ks + u1 * 8);
    sv0 = *(const uint4*)(Vs + u0 * 8);
    sv1 = *(const uint4*)(Vs + u1 * 8);
  };
  auto stage_store = [&](u16* Kd, u16* Vd) {
    *(uint4*)(Kd + l0) = sk0;
    *(uint4*)(Kd + l1) = sk1;
    *(uint4*)(Vd + l0) = sv0;
    *(uint4*)(Vd + l1) = sv1;
  };

  stage_load(0);
  stage_store(Kl[0], Vl[0]);
  __syncthreads();

  const u16* Kcur = Kl[0];
  const u16* Vcur = Vl[0];
  u16* Knxt = Kl[1];
  u16* Vnxt = Vl[1];

#pragma unroll 1
  for (int kc = 0; kc < 16; ++kc) {
    if (kc < 15) stage_load(kc + 1);

#pragma unroll
    for (int t2 = 0; t2 < 2; ++t2) {  // 32-key subchunk
      bf16x8 kf0[2], kf1[2], vf[4];
#pragma unroll
      for (int tt = 0; tt < 2; ++tt) {
        const u16* Kb = Kcur + (t2 * 32 + tt * 16 + mm) * 64;
        kf0[tt] = *(const bf16x8*)(Kb + ((q ^ m7) * 8));
        kf1[tt] = *(const bf16x8*)(Kb + (((q + 4) ^ m7) * 8));
      }
#pragma unroll
      for (int ct = 0; ct < 4; ++ct) {
        const u16* Vb = Vcur + (ct * 16 + mm) * 64;
        vf[ct] = *(const bf16x8*)(Vb + (((t2 * 4 + q) ^ m7) * 8));
      }

#pragma unroll
      for (int qt = 0; qt < 2; ++qt) {
#pragma unroll
        for (int tt = 0; tt < 2; ++tt) {
          f32x4 s = {0.f, 0.f, 0.f, 0.f};
          s = MFMA(kf0[tt], qa0[qt], s);
          s = MFMA(kf1[tt], qa1[qt], s);
          const float e0 = __expf(s[0]), e1 = __expf(s[1]);
          const float e2 = __expf(s[2]), e3 = __expf(s[3]);
          rp[qt] += (e0 + e1) + (e2 + e3);
          // P[key=tt*16+q*4+r][query=mm] -> ps[query][key], packed pairs
          *(u32*)&ps[w][mm][tt * 16 + q * 4] = packbf_t(e1, e0);
          *(u32*)&ps[w][mm][tt * 16 + q * 4 + 2] = packbf_t(e3, e2);
        }
        // B-operand read: B[k=q*8+j][n=mm] (same-wave DS ordering)
        const bf16x8 pb = *(const bf16x8*)&ps[w][mm][q * 8];
#pragma unroll
        for (int ct = 0; ct < 4; ++ct) z[qt][ct] = MFMA(vf[ct], pb, z[qt][ct]);
      }
    }

    if (kc < 15) stage_store(Knxt, Vnxt);
    __syncthreads();
    const u16* tk = Kcur; Kcur = Knxt; Knxt = (u16*)tk;
    const u16* tv = Vcur; Vcur = Vnxt; Vnxt = (u16*)tv;
  }

  // rowsum for query mm: reduce over 4 quads, normalize, store (B,N,128).
#pragma unroll
  for (int qt = 0; qt < 2; ++qt) {
    float v = rp[qt];
    v += __shfl_xor(v, 16);
    v += __shfl_xor(v, 32);
    const float rinv = __builtin_amdgcn_rcpf(v);
    u16* Zr = Ztb + (b * 1024 + q0 + qt * 16 + mm) * 128 + br * 64;
#pragma unroll
    for (int ct = 0; ct < 4; ++ct) {
      uint2 val;
      val.x = packbf(z[qt][ct][0] * rinv, z[qt][ct][1] * rinv);
      val.y = packbf(z[qt][ct][2] * rinv, z[qt][ct][3] * rinv);
      *(uint2*)(Zr + ct * 16 + q * 4) = val;
    }
  }
}

// ---------------------------------------------------------------------------
// Kernel 3: fused zproj (128->128) + final (192->192) + gates, all MFMA.
// grid (32,16).
// ---------------------------------------------------------------------------
__global__ __launch_bounds__(256) void tail_kernel(
    const u16* __restrict__ Ztb, const u16* __restrict__ hbuf,
    const float* __restrict__ m_, const u16* __restrict__ Wzb,
    const float* __restrict__ bz, const u16* __restrict__ Wmb,
    const float* __restrict__ bmp, float* __restrict__ out)
{
  const int b = blockIdx.y, n0 = blockIdx.x * 32;
  __shared__ __align__(16) u16 zp[32][136];  // bf16 Zp tile [px][c]
  const int tid = threadIdx.x, lane = tid & 63, wv = tid >> 6;
  const int mm = lane & 15, q = lane >> 4;
  const int pxt = wv & 1, oh = wv >> 1;

  // ---- Phase A: Zp = Wz @ [Zh;Zm] + bz  (A=W: lane rows = contiguous o-ch)
  {
    bf16x8 za[4];
#pragma unroll
    for (int ks = 0; ks < 4; ++ks)
      za[ks] = *(const bf16x8*)(Ztb + (b * 1024 + n0 + pxt * 16 + mm) * 128 +
                                ks * 32 + q * 8);
#pragma unroll
    for (int ot = 0; ot < 4; ++ot) {
      const int o0 = oh * 64 + ot * 16;
      const float4 b4 = *(const float4*)(bz + o0 + q * 4);
      f32x4 d = {b4.x, b4.y, b4.z, b4.w};
#pragma unroll
      for (int ks = 0; ks < 4; ++ks) {
        const bf16x8 wb = *(const bf16x8*)(Wzb + (o0 + mm) * 128 + ks * 32 + q * 8);
        d = MFMA(wb, za[ks], d);
      }
      uint2 val;
      val.x = packbf(d[0], d[1]);
      val.y = packbf(d[2], d[3]);
      *(uint2*)&zp[pxt * 16 + mm][o0 + q * 4] = val;
    }
  }
  __syncthreads();

  // ---- Phase B: combined = Wm @ [Zp; h] + bm (rows gate-major-permuted)
  {
    const int hb2 = oh;
    bf16x8 fa[6];
#pragma unroll
    for (int ks = 0; ks < 4; ++ks)
      fa[ks] = *(const bf16x8*)&zp[pxt * 16 + mm][ks * 32 + q * 8];
    {
      const u16* hp = hbuf + (b * 1024 + n0 + pxt * 16 + mm) * 64;
      fa[4] = *(const bf16x8*)(hp + q * 8);
      fa[5] = *(const bf16x8*)(hp + 32 + q * 8);
    }
    f32x4 dd[6];
#pragma unroll
    for (int j = 0; j < 6; ++j) {
      const int p = hb2 * 96 + j * 16 + mm;
      const float bb = bmp[p];
      f32x4 d = {bb, bb, bb, bb};
#pragma unroll
      for (int ks = 0; ks < 6; ++ks) {
        const bf16x8 wb = *(const bf16x8*)(Wmb + p * 192 + ks * 32 + q * 8);
        d = MFMA(fa[ks], wb, d);
      }
      dd[j] = d;
    }
#pragma unroll
    for (int ctl = 0; ctl < 2; ++ctl) {
      const int c = (hb2 * 2 + ctl) * 16 + mm;
      const int px = n0 + pxt * 16 + q * 4;
      const float4 mold = *(const float4*)(m_ + (b * 64 + c) * 1024 + px);
      float4 nh, nm;
#pragma unroll
      for (int r = 0; r < 4; ++r) {
        const float xo = dd[ctl * 3 + 0][r];
        const float xg = dd[ctl * 3 + 1][r];
        const float xi = dd[ctl * 3 + 2][r];
        const float si = __builtin_amdgcn_rcpf(1.f + __expf(-xi));
        const float th = 1.f - 2.f * __builtin_amdgcn_rcpf(__expf(2.f * xg) + 1.f);
        const float so = __builtin_amdgcn_rcpf(1.f + __expf(-xo));
        const float mo = ((const float*)&mold)[r];
        const float nmv = (1.f - si) * mo + si * th;
        ((float*)&nm)[r] = nmv;
        ((float*)&nh)[r] = so * nmv;
      }
      *(float4*)(out + (b * 64 + c) * 1024 + px) = nh;
      *(float4*)(out + 1048576 + (b * 64 + c) * 1024 + px) = nm;
    }
  }
}

// ---------------------------------------------------------------------------
extern "C" void kernel_launch(void* const* d_in, const int* in_sizes, int n_in,
                              void* d_out, int out_size, void* d_ws, size_t ws_size,
                              hipStream_t stream) {
  const float* h   = (const float*)d_in[0];
  const float* m   = (const float*)d_in[1];
  const float* Wq  = (const float*)d_in[2];
  const float* bq  = (const float*)d_in[3];
  const float* Wk  = (const float*)d_in[4];
  const float* bk  = (const float*)d_in[5];
  const float* Wk2 = (const float*)d_in[6];
  const float* bk2 = (const float*)d_in[7];
  const float* Wv  = (const float*)d_in[8];
  const float* bv  = (const float*)d_in[9];
  const float* Wv2 = (const float*)d_in[10];
  const float* bv2 = (const float*)d_in[11];
  const float* Wz  = (const float*)d_in[12];
  const float* bz  = (const float*)d_in[13];
  const float* Wm  = (const float*)d_in[14];
  const float* bm  = (const float*)d_in[15];
  float* out = (float*)d_out;

  char* ws = (char*)d_ws;
  const size_t MB = 1024 * 1024;
  u16* Qb   = (u16*)(ws + 0 * MB);       // (B,N,64)
  u16* Khb  = (u16*)(ws + 2 * MB);
  u16* Kmb  = (u16*)(ws + 4 * MB);
  u16* Vhb  = (u16*)(ws + 6 * MB);       // blocked (b,kc,c,64)
  u16* Vmb  = (u16*)(ws + 8 * MB);
  u16* hbuf = (u16*)(ws + 10 * MB);      // (B,N,64)
  u16* Ztb  = (u16*)(ws + 12 * MB);      // (B,N,128)
  u16* W5   = (u16*)(ws + 16 * MB);               // 5x 64x64 bf16
  u16* Wzb  = (u16*)(ws + 16 * MB + 40960);       // 128x128
  u16* Wmb  = (u16*)(ws + 16 * MB + 73728);       // 192x192 permuted
  float* bmp = (float*)(ws + 16 * MB + 147456);   // 192 permuted

  prep_kernel<<<289, 256, 0, stream>>>(Wq, Wk, Wk2, Wv, Wv2, Wz, Wm, bm,
                                       W5, Wzb, Wmb, bmp);
  proj_kernel<<<dim3(16, 16, 2), 256, 0, stream>>>(h, m, bq, bk, bk2, bv, bv2, W5,
                                                   Qb, Khb, Kmb, Vhb, Vmb, hbuf);
  attn_kernel<<<256, 256, 0, stream>>>(Qb, Khb, Kmb, Vhb, Vmb, Ztb);
  tail_kernel<<<dim3(32, 16), 256, 0, stream>>>(Ztb, hbuf, m, Wzb, bz, Wmb, bmp, out);
}

// Round 6
// 135.992 us; speedup vs baseline: 1.3119x; 1.0416x over previous
//
#include <hip/hip_runtime.h>

typedef unsigned short u16;
typedef unsigned int u32;
typedef __attribute__((ext_vector_type(8))) short bf16x8;
typedef __attribute__((ext_vector_type(4))) short bf16x4;
typedef __attribute__((ext_vector_type(4))) float f32x4;

#define MFMA(a, b, c) __builtin_amdgcn_mfma_f32_16x16x32_bf16((a), (b), (c), 0, 0, 0)
#define MFMA16(a, b, c) __builtin_amdgcn_mfma_f32_16x16x16bf16_1k((a), (b), (c), 0, 0, 0)

// round-to-nearest-even f32 -> bf16
static __device__ __forceinline__ u16 f2bf(float x) {
  u32 u = __float_as_uint(x);
  u += 0x7FFFu + ((u >> 16) & 1u);
  return (u16)(u >> 16);
}
// pack two f32 -> (bf16(hi)<<16)|bf16(lo), truncating (hot paths)
static __device__ __forceinline__ u32 packbf_t(float hi, float lo) {
  return __builtin_amdgcn_perm(__float_as_uint(hi), __float_as_uint(lo), 0x07060302u);
}
// rounded pack: lo | hi<<16
static __device__ __forceinline__ u32 packbf(float lo, float hi) {
  return (u32)f2bf(lo) | ((u32)f2bf(hi) << 16);
}

// ---------------------------------------------------------------------------
// Kernel 0: weight prep (bf16 conversion + gate-major permute of Wm).
// ---------------------------------------------------------------------------
__global__ void prep_kernel(const float* __restrict__ Wq, const float* __restrict__ Wk,
                            const float* __restrict__ Wk2, const float* __restrict__ Wv,
                            const float* __restrict__ Wv2, const float* __restrict__ Wz,
                            const float* __restrict__ Wm, const float* __restrict__ bm,
                            u16* __restrict__ W5, u16* __restrict__ Wzb,
                            u16* __restrict__ Wmb, float* __restrict__ bmp) {
  const int id = blockIdx.x * 256 + threadIdx.x;
  if (id < 20480) {
    const int wi = id >> 12, e = id & 4095;
    const float* src = wi == 0 ? Wq : wi == 1 ? Wk : wi == 2 ? Wk2 : wi == 3 ? Wv : Wv2;
    W5[id] = f2bf(src[e]);
  } else if (id < 36864) {
    const int e = id - 20480;
    Wzb[e] = f2bf(Wz[e]);
  } else if (id < 73728) {
    const int e = id - 36864;
    const int p = e / 192, k = e % 192;
    const int hb2 = p / 96, r1 = p % 96, ctl = r1 / 48, r2 = r1 % 48;
    const int g = r2 >> 4, mm = r2 & 15;
    const int o = g * 64 + (hb2 * 2 + ctl) * 16 + mm;
    Wmb[p * 192 + k] = f2bf(Wm[o * 192 + k]);
  } else if (id < 73920) {
    const int p = id - 73728;
    const int hb2 = p / 96, r1 = p % 96, ctl = r1 / 48, r2 = r1 % 48;
    const int g = r2 >> 4, mm = r2 & 15;
    const int o = g * 64 + (hb2 * 2 + ctl) * 16 + mm;
    bmp[p] = bm[o];
  }
}

// ---------------------------------------------------------------------------
// Kernel 1: 1x1-conv projections via bf16 MFMA, packed uint2 stores.
// Q/K: (B,N,64). V: BLOCKED (b, kc=n/64, c, 64keys). grid (16,16,2).
// ---------------------------------------------------------------------------
__global__ __launch_bounds__(256) void proj_kernel(
    const float* __restrict__ h, const float* __restrict__ m_,
    const float* __restrict__ bq, const float* __restrict__ bk,
    const float* __restrict__ bk2, const float* __restrict__ bv,
    const float* __restrict__ bv2, const u16* __restrict__ W5,
    u16* __restrict__ Qb, u16* __restrict__ Khb, u16* __restrict__ Kmb,
    u16* __restrict__ Vhb, u16* __restrict__ Vmb, u16* __restrict__ hbuf)
{
  const int b = blockIdx.y, n0 = blockIdx.x * 64, z = blockIdx.z;
  __shared__ __align__(16) u16 xt[64][72];  // [px][c] bf16
  const int tid = threadIdx.x;
  const float* __restrict__ X = z ? m_ : h;

  {
    const int px = tid & 63, c0 = (tid >> 6) * 16;
#pragma unroll
    for (int i = 0; i < 8; ++i) {
      const int c = c0 + 2 * i;
      const float f0 = X[(b * 64 + c) * 1024 + n0 + px];
      const float f1 = X[(b * 64 + c + 1) * 1024 + n0 + px];
      *(u32*)&xt[px][c] = packbf(f0, f1);
    }
  }
  __syncthreads();

  const int lane = tid & 63, w = tid >> 6;  // w = 16-px tile
  const int mm = lane & 15, q = lane >> 4;

  const bf16x8 xa0 = *(const bf16x8*)&xt[w * 16 + mm][q * 8];
  const bf16x8 xa1 = *(const bf16x8*)&xt[w * 16 + mm][32 + q * 8];

  auto qk_store = [&](u16* dst, const u16* Wb, const float* bias) {
#pragma unroll
    for (int ot = 0; ot < 4; ++ot) {
      const bf16x8 wb0 = *(const bf16x8*)(Wb + (ot * 16 + mm) * 64 + q * 8);
      const bf16x8 wb1 = *(const bf16x8*)(Wb + (ot * 16 + mm) * 64 + 32 + q * 8);
      const float4 b4 = *(const float4*)(bias + ot * 16 + q * 4);
      f32x4 d = {b4.x, b4.y, b4.z, b4.w};
      d = MFMA(wb0, xa0, d);
      d = MFMA(wb1, xa1, d);
      uint2 val;
      val.x = packbf(d[0], d[1]);
      val.y = packbf(d[2], d[3]);
      *(uint2*)(dst + (b * 1024 + n0 + w * 16 + mm) * 64 + ot * 16 + q * 4) = val;
    }
  };
  auto v_store = [&](u16* dst, const u16* Wb, const float* bias) {
#pragma unroll
    for (int ot = 0; ot < 4; ++ot) {
      const bf16x8 wb0 = *(const bf16x8*)(Wb + (ot * 16 + mm) * 64 + q * 8);
      const bf16x8 wb1 = *(const bf16x8*)(Wb + (ot * 16 + mm) * 64 + 32 + q * 8);
      const float bb = bias[ot * 16 + mm];
      f32x4 d = {bb, bb, bb, bb};
      d = MFMA(xa0, wb0, d);
      d = MFMA(xa1, wb1, d);
      uint2 val;
      val.x = packbf(d[0], d[1]);
      val.y = packbf(d[2], d[3]);
      *(uint2*)(dst + b * 65536 + blockIdx.x * 4096 + (ot * 16 + mm) * 64 +
                w * 16 + q * 4) = val;
    }
  };

  if (z == 0) {
    qk_store(Qb, W5, bq);
    qk_store(Khb, W5 + 4096, bk);
    v_store(Vhb, W5 + 3 * 4096, bv);
    const int px = tid >> 2, sg = tid & 3;
    u32* dst = (u32*)(hbuf + (b * 1024 + n0 + px) * 64 + sg * 16);
    const u16* srcr = &xt[px][sg * 16];
#pragma unroll
    for (int j = 0; j < 8; ++j) dst[j] = *(const u32*)(srcr + 2 * j);
  } else {
    qk_store(Kmb, W5 + 2 * 4096, bk2);
    v_store(Vmb, W5 + 4 * 4096, bv2);
  }
}

// ---------------------------------------------------------------------------
// Kernel 2: fused attention, key-split flash with zero-transpose PV.
// Block = 64 queries x 4 waves; wave w owns 16-key slice of each 64-key
// chunk. S^T = K_slice . Q^T (16x16x32) leaves exp(P) in C/D layout
// [key=quad*4+r][query=mm], which IS the B-operand layout of the K=16
// MFMA (k=quad*4+j, n=lane&15) -> PV via v_mfma_f32_16x16x16_bf16 with
// NO transpose, NO LDS round-trip, NO shuffles. K/V double-buffer-staged
// in LDS (padded rows, <=2-way banks). Each wave holds full 64x64 Z
// partial; bf16 LDS combine at end (overlays dead stage buffers).
// grid 512 = 16 b (XCD-affine) x 2 br x 16 qh; 2 blocks/CU.
// ---------------------------------------------------------------------------
__global__ __launch_bounds__(256) void attn_kernel(
    const u16* __restrict__ Qb, const u16* __restrict__ Khb,
    const u16* __restrict__ Kmb, const u16* __restrict__ Vhb,
    const u16* __restrict__ Vmb, u16* __restrict__ Ztb)
{
  const int id = blockIdx.x;
  const int b = id & 15;            // batch -> fixed XCD
  const int br = (id >> 4) & 1;
  const int qh = id >> 5;           // 0..15
  const u16* __restrict__ K = (br ? Kmb : Khb) + b * 65536;  // (N,64)
  const u16* __restrict__ V = (br ? Vmb : Vhb) + b * 65536;  // blocked (kc,c,64)

  __shared__ __align__(16) u16 pool[18432];  // Kl[2][64][72] + Vl[2][64][72] / zcb overlay
  __shared__ float rsw[4][64];
  u16* const Kl = pool;            // 2 * 4608 u16
  u16* const Vl = pool + 9216;     // 2 * 4608 u16

  const int tid = threadIdx.x, w = tid >> 6, lane = tid & 63;
  const int mm = lane & 15, q = lane >> 4;
  const int q0 = qh * 64;

  // Q B-operand frags for 4 query tiles: B[n=query=mm][k=d=q*8+j]
  bf16x8 qb0[4], qb1[4];
#pragma unroll
  for (int qt = 0; qt < 4; ++qt) {
    const u16* Qp = Qb + (b * 1024 + q0 + qt * 16 + mm) * 64;
    qb0[qt] = *(const bf16x8*)(Qp + q * 8);
    qb1[qt] = *(const bf16x8*)(Qp + 32 + q * 8);
  }

  f32x4 z[4][4];  // [qt][ct] = Z[c=ct*16+q*4+r][query=qt*16+mm] partial
#pragma unroll
  for (int qt = 0; qt < 4; ++qt)
#pragma unroll
    for (int ct = 0; ct < 4; ++ct) z[qt][ct] = (f32x4){0.f, 0.f, 0.f, 0.f};
  float rp[4] = {0.f, 0.f, 0.f, 0.f};

  // staging: 512 16B-units K + 512 V; thread handles K units {t, t+256}, same V.
  const int so0 = (tid >> 3) * 72 + (tid & 7) * 8;
  const int so1 = so0 + 32 * 72;
  uint4 sk0, sk1, sv0, sv1;
  auto stage_load = [&](int kc) {
    const u16* Ks = K + kc * 4096;
    const u16* Vs = V + kc * 4096;
    sk0 = *(const uint4*)(Ks + tid * 8);
    sk1 = *(const uint4*)(Ks + tid * 8 + 2048);
    sv0 = *(const uint4*)(Vs + tid * 8);
    sv1 = *(const uint4*)(Vs + tid * 8 + 2048);
  };
  auto stage_store = [&](int buf) {
    u16* Kd = Kl + buf * 4608;
    u16* Vd = Vl + buf * 4608;
    *(uint4*)(Kd + so0) = sk0;
    *(uint4*)(Kd + so1) = sk1;
    *(uint4*)(Vd + so0) = sv0;
    *(uint4*)(Vd + so1) = sv1;
  };

  stage_load(0);
  stage_store(0);
  __syncthreads();

  int cur = 0;
#pragma unroll 1
  for (int kc = 0; kc < 16; ++kc) {
    if (kc < 15) stage_load(kc + 1);

    const u16* Kc = Kl + cur * 4608;
    const u16* Vc = Vl + cur * 4608;
    // A-operand K frags for this wave's 16-key slice: A[m=key=mm][k=d]
    const bf16x8 kf0 = *(const bf16x8*)(Kc + (w * 16 + mm) * 72 + q * 8);
    const bf16x8 kf1 = *(const bf16x8*)(Kc + (w * 16 + mm) * 72 + 32 + q * 8);
    // A-operand V frags: A[m=c=mm][k=key=q*4+i] for this wave's slice
    bf16x4 vf[4];
#pragma unroll
    for (int ct = 0; ct < 4; ++ct)
      vf[ct] = *(const bf16x4*)(Vc + (ct * 16 + mm) * 72 + w * 16 + q * 4);

#pragma unroll
    for (int qt = 0; qt < 4; ++qt) {
      f32x4 s = {0.f, 0.f, 0.f, 0.f};
      s = MFMA(kf0, qb0[qt], s);
      s = MFMA(kf1, qb1[qt], s);
      const float e0 = __expf(s[0]), e1 = __expf(s[1]);
      const float e2 = __expf(s[2]), e3 = __expf(s[3]);
      rp[qt] += (e0 + e1) + (e2 + e3);
      union { u32 u[2]; bf16x4 v; } pb;
      pb.u[0] = packbf_t(e1, e0);   // B[k=q*4+{0,1}][n=mm]
      pb.u[1] = packbf_t(e3, e2);   // B[k=q*4+{2,3}][n=mm]
#pragma unroll
      for (int ct = 0; ct < 4; ++ct) z[qt][ct] = MFMA16(vf[ct], pb.v, z[qt][ct]);
    }

    if (kc < 15) stage_store(cur ^ 1);
    __syncthreads();
    cur ^= 1;
  }

  // publish: zcb overlays the (dead) stage buffers. [w][query][c], rows 68.
  u16* const zcb = pool;
#pragma unroll
  for (int qt = 0; qt < 4; ++qt) {
    float v = rp[qt];
    v += __shfl_xor(v, 16);
    v += __shfl_xor(v, 32);
    if (q == 0) rsw[w][qt * 16 + mm] = v;
#pragma unroll
    for (int ct = 0; ct < 4; ++ct) {
      uint2 val;
      val.x = packbf_t(z[qt][ct][1], z[qt][ct][0]);
      val.y = packbf_t(z[qt][ct][3], z[qt][ct][2]);
      *(uint2*)(zcb + w * 4352 + (qt * 16 + mm) * 68 + ct * 16 + q * 4) = val;
    }
  }
  __syncthreads();

  // combine 4 key-splits, normalize, store bf16 (B,N,128)
  const int c2 = tid & 31, qr = tid >> 5;
#pragma unroll
  for (int i = 0; i < 8; ++i) {
    const int query = qr + i * 8;
    const float rt = rsw[0][query] + rsw[1][query] + rsw[2][query] + rsw[3][query];
    const float rinv = __builtin_amdgcn_rcpf(rt);
    float vlo = 0.f, vhi = 0.f;
#pragma unroll
    for (int ww = 0; ww < 4; ++ww) {
      const u32 u = *(const u32*)(zcb + ww * 4352 + query * 68 + c2 * 2);
      vlo += __uint_as_float(u << 16);
      vhi += __uint_as_float(u & 0xffff0000u);
    }
    vlo *= rinv;
    vhi *= rinv;
    *(u32*)(Ztb + (b * 1024 + q0 + query) * 128 + br * 64 + c2 * 2) = packbf_t(vhi, vlo);
  }
}

// ---------------------------------------------------------------------------
// Kernel 3: fused zproj (128->128) + final (192->192) + gates, all MFMA.
// grid (32,16).
// ---------------------------------------------------------------------------
__global__ __launch_bounds__(256) void tail_kernel(
    const u16* __restrict__ Ztb, const u16* __restrict__ hbuf,
    const float* __restrict__ m_, const u16* __restrict__ Wzb,
    const float* __restrict__ bz, const u16* __restrict__ Wmb,
    const float* __restrict__ bmp, float* __restrict__ out)
{
  const int b = blockIdx.y, n0 = blockIdx.x * 32;
  __shared__ __align__(16) u16 zp[32][136];  // bf16 Zp tile [px][c]
  const int tid = threadIdx.x, lane = tid & 63, wv = tid >> 6;
  const int mm = lane & 15, q = lane >> 4;
  const int pxt = wv & 1, oh = wv >> 1;

  // ---- Phase A: Zp = Wz @ [Zh;Zm] + bz  (A=W: lane rows = contiguous o-ch)
  {
    bf16x8 za[4];
#pragma unroll
    for (int ks = 0; ks < 4; ++ks)
      za[ks] = *(const bf16x8*)(Ztb + (b * 1024 + n0 + pxt * 16 + mm) * 128 +
                                ks * 32 + q * 8);
#pragma unroll
    for (int ot = 0; ot < 4; ++ot) {
      const int o0 = oh * 64 + ot * 16;
      const float4 b4 = *(const float4*)(bz + o0 + q * 4);
      f32x4 d = {b4.x, b4.y, b4.z, b4.w};
#pragma unroll
      for (int ks = 0; ks < 4; ++ks) {
        const bf16x8 wb = *(const bf16x8*)(Wzb + (o0 + mm) * 128 + ks * 32 + q * 8);
        d = MFMA(wb, za[ks], d);
      }
      uint2 val;
      val.x = packbf(d[0], d[1]);
      val.y = packbf(d[2], d[3]);
      *(uint2*)&zp[pxt * 16 + mm][o0 + q * 4] = val;
    }
  }
  __syncthreads();

  // ---- Phase B: combined = Wm @ [Zp; h] + bm (rows gate-major-permuted)
  {
    const int hb2 = oh;
    bf16x8 fa[6];
#pragma unroll
    for (int ks = 0; ks < 4; ++ks)
      fa[ks] = *(const bf16x8*)&zp[pxt * 16 + mm][ks * 32 + q * 8];
    {
      const u16* hp = hbuf + (b * 1024 + n0 + pxt * 16 + mm) * 64;
      fa[4] = *(const bf16x8*)(hp + q * 8);
      fa[5] = *(const bf16x8*)(hp + 32 + q * 8);
    }
    f32x4 dd[6];
#pragma unroll
    for (int j = 0; j < 6; ++j) {
      const int p = hb2 * 96 + j * 16 + mm;
      const float bb = bmp[p];
      f32x4 d = {bb, bb, bb, bb};
#pragma unroll
      for (int ks = 0; ks < 6; ++ks) {
        const bf16x8 wb = *(const bf16x8*)(Wmb + p * 192 + ks * 32 + q * 8);
        d = MFMA(fa[ks], wb, d);
      }
      dd[j] = d;
    }
#pragma unroll
    for (int ctl = 0; ctl < 2; ++ctl) {
      const int c = (hb2 * 2 + ctl) * 16 + mm;
      const int px = n0 + pxt * 16 + q * 4;
      const float4 mold = *(const float4*)(m_ + (b * 64 + c) * 1024 + px);
      float4 nh, nm;
#pragma unroll
      for (int r = 0; r < 4; ++r) {
        const float xo = dd[ctl * 3 + 0][r];
        const float xg = dd[ctl * 3 + 1][r];
        const float xi = dd[ctl * 3 + 2][r];
        const float si = __builtin_amdgcn_rcpf(1.f + __expf(-xi));
        const float th = 1.f - 2.f * __builtin_amdgcn_rcpf(__expf(2.f * xg) + 1.f);
        const float so = __builtin_amdgcn_rcpf(1.f + __expf(-xo));
        const float mo = ((const float*)&mold)[r];
        const float nmv = (1.f - si) * mo + si * th;
        ((float*)&nm)[r] = nmv;
        ((float*)&nh)[r] = so * nmv;
      }
      *(float4*)(out + (b * 64 + c) * 1024 + px) = nh;
      *(float4*)(out + 1048576 + (b * 64 + c) * 1024 + px) = nm;
    }
  }
}

// ---------------------------------------------------------------------------
extern "C" void kernel_launch(void* const* d_in, const int* in_sizes, int n_in,
                              void* d_out, int out_size, void* d_ws, size_t ws_size,
                              hipStream_t stream) {
  const float* h   = (const float*)d_in[0];
  const float* m   = (const float*)d_in[1];
  const float* Wq  = (const float*)d_in[2];
  const float* bq  = (const float*)d_in[3];
  const float* Wk  = (const float*)d_in[4];
  const float* bk  = (const float*)d_in[5];
  const float* Wk2 = (const float*)d_in[6];
  const float* bk2 = (const float*)d_in[7];
  const float* Wv  = (const float*)d_in[8];
  const float* bv  = (const float*)d_in[9];
  const float* Wv2 = (const float*)d_in[10];
  const float* bv2 = (const float*)d_in[11];
  const float* Wz  = (const float*)d_in[12];
  const float* bz  = (const float*)d_in[13];
  const float* Wm  = (const float*)d_in[14];
  const float* bm  = (const float*)d_in[15];
  float* out = (float*)d_out;

  char* ws = (char*)d_ws;
  const size_t MB = 1024 * 1024;
  u16* Qb   = (u16*)(ws + 0 * MB);       // (B,N,64)
  u16* Khb  = (u16*)(ws + 2 * MB);
  u16* Kmb  = (u16*)(ws + 4 * MB);
  u16* Vhb  = (u16*)(ws + 6 * MB);       // blocked (b,kc,c,64)
  u16* Vmb  = (u16*)(ws + 8 * MB);
  u16* hbuf = (u16*)(ws + 10 * MB);      // (B,N,64)
  u16* Ztb  = (u16*)(ws + 12 * MB);      // (B,N,128)
  u16* W5   = (u16*)(ws + 16 * MB);               // 5x 64x64 bf16
  u16* Wzb  = (u16*)(ws + 16 * MB + 40960);       // 128x128
  u16* Wmb  = (u16*)(ws + 16 * MB + 73728);       // 192x192 permuted
  float* bmp = (float*)(ws + 16 * MB + 147456);   // 192 permuted

  prep_kernel<<<289, 256, 0, stream>>>(Wq, Wk, Wk2, Wv, Wv2, Wz, Wm, bm,
                                       W5, Wzb, Wmb, bmp);
  proj_kernel<<<dim3(16, 16, 2), 256, 0, stream>>>(h, m, bq, bk, bk2, bv, bv2, W5,
                                                   Qb, Khb, Kmb, Vhb, Vmb, hbuf);
  attn_kernel<<<512, 256, 0, stream>>>(Qb, Khb, Kmb, Vhb, Vmb, Ztb);
  tail_kernel<<<dim3(32, 16), 256, 0, stream>>>(Ztb, hbuf, m, Wzb, bz, Wmb, bmp, out);
}